// Round 1
// baseline (2885.045 us; speedup 1.0000x reference)
//
#include <hip/hip_runtime.h>

typedef __attribute__((ext_vector_type(8))) short short8;
typedef __attribute__((ext_vector_type(4))) float floatx4;

__device__ __forceinline__ unsigned short f2bf(float f) {
  unsigned u = __float_as_uint(f);
  u += 0x7FFFu + ((u >> 16) & 1u);
  return (unsigned short)(u >> 16);
}
__device__ __forceinline__ float bf2f(unsigned short b) {
  return __uint_as_float(((unsigned)b) << 16);
}

// ---- prep: feat->bf16; W1 [3,128,128] -> W1T [3][n=128][k=128] bf16;
//            W2 [3,128,64] -> W2T [3][n=64][k=128] bf16 ----
__global__ __launch_bounds__(256) void prep_k(
    const float* __restrict__ feat, const float* __restrict__ W1,
    const float* __restrict__ W2, unsigned short* __restrict__ featb,
    unsigned short* __restrict__ w1t, unsigned short* __restrict__ w2t) {
  int tid = blockIdx.x * 256 + threadIdx.x;
  if (tid < 1600000) {                    // 50000*128/4 float4s
    float4 v = ((const float4*)feat)[tid];
    ushort4 o;
    o.x = f2bf(v.x); o.y = f2bf(v.y); o.z = f2bf(v.z); o.w = f2bf(v.w);
    ((ushort4*)featb)[tid] = o;
  } else if (tid < 1600000 + 49152) {     // W1T
    int t = tid - 1600000;
    int r = t >> 14, rem = t & 16383, n = rem >> 7, k = rem & 127;
    w1t[t] = f2bf(W1[(r << 14) + (k << 7) + n]);
  } else if (tid < 1600000 + 49152 + 24576) {  // W2T
    int t = tid - 1649152;
    int r = t >> 13, rem = t & 8191, n = rem >> 7, k = rem & 127;
    w2t[t] = f2bf(W2[(r << 13) + (k << 6) + n]);
  }
}

// ---- layer-1 aggregation: s1[r][dst] += feat[src]; deg1[r][dst] += 1 ----
__global__ __launch_bounds__(256) void agg1_k(
    const int* __restrict__ src, const int* __restrict__ dst,
    const unsigned short* __restrict__ featb,
    float* __restrict__ s1, float* __restrict__ deg1) {
  int lane = threadIdx.x & 63;
  int wid = blockIdx.x * 4 + (threadIdx.x >> 6);
  int nw = gridDim.x * 4;
  for (int i = wid; i < 2400000; i += nw) {
    int r = i / 800000;
    int s = src[i], d = dst[i];
    unsigned pair = *(const unsigned*)(featb + (s << 7) + (lane << 1));
    float v0 = __uint_as_float(pair << 16);
    float v1 = __uint_as_float(pair & 0xFFFF0000u);
    float* p = s1 + ((r * 50000 + d) << 7) + (lane << 1);
    unsafeAtomicAdd(p, v0);
    unsafeAtomicAdd(p + 1, v1);
    if (lane == 0) unsafeAtomicAdd(deg1 + r * 50000 + d, 1.0f);
  }
}

// ---- layer-2 aggregation: s2[r][dst] += Wh2[r][src]; deg2 += 1 ----
__global__ __launch_bounds__(256) void agg2_k(
    const int* __restrict__ src, const int* __restrict__ dst,
    const unsigned short* __restrict__ wh2,
    float* __restrict__ s2, float* __restrict__ deg2) {
  int lane = threadIdx.x & 63;
  int wid = blockIdx.x * 4 + (threadIdx.x >> 6);
  int nw = gridDim.x * 4;
  for (int i = wid; i < 2400000; i += nw) {
    int r = i / 800000;
    int s = src[i], d = dst[i];
    float v = bf2f(wh2[((r * 50000 + s) << 6) + lane]);
    unsafeAtomicAdd(s2 + ((r * 50000 + d) << 6) + lane, v);
    if (lane == 0) unsafeAtomicAdd(deg2 + r * 50000 + d, 1.0f);
  }
}

// ---- GEMM1: h = leaky( sum_r (s1_r/max(deg,1)) @ W1_r + b1_r*[deg>0] ), bf16 out
// M=50000 (BM=64, 4 waves x 16 rows), N=128 (8 frags), K=384 concat ----
__global__ __launch_bounds__(256) void gemm1_k(
    const float* __restrict__ s1, const float* __restrict__ deg1,
    const unsigned short* __restrict__ w1t, const float* __restrict__ b1,
    unsigned short* __restrict__ hb) {
  int lane = threadIdx.x & 63;
  int wave = threadIdx.x >> 6;
  int rbase = blockIdx.x * 64 + wave * 16;
  int arow = rbase + (lane & 15);
  int anode = arow < 50000 ? arow : 49999;
  int kg = lane >> 4;

  float sc[3];
#pragma unroll
  for (int r = 0; r < 3; ++r) {
    float dg = deg1[r * 50000 + anode];
    sc[r] = 1.0f / fmaxf(dg, 1.0f);
  }
  const floatx4 fzero = {0.f, 0.f, 0.f, 0.f};
  floatx4 acc[8];
#pragma unroll
  for (int f = 0; f < 8; ++f) acc[f] = fzero;

  for (int ks = 0; ks < 12; ++ks) {
    int r = ks >> 2;
    int k0 = ((ks & 3) << 5) + (kg << 3);
    const float* ap = s1 + ((r * 50000 + anode) << 7) + k0;
    float4 a0 = *(const float4*)ap;
    float4 a1 = *(const float4*)(ap + 4);
    float sr = sc[r];
    short8 af;
    af[0] = (short)f2bf(a0.x * sr); af[1] = (short)f2bf(a0.y * sr);
    af[2] = (short)f2bf(a0.z * sr); af[3] = (short)f2bf(a0.w * sr);
    af[4] = (short)f2bf(a1.x * sr); af[5] = (short)f2bf(a1.y * sr);
    af[6] = (short)f2bf(a1.z * sr); af[7] = (short)f2bf(a1.w * sr);
#pragma unroll
    for (int f = 0; f < 8; ++f) {
      int n = (f << 4) + (lane & 15);
      short8 bf = *(const short8*)(w1t + (r << 14) + (n << 7) + k0);
      acc[f] = __builtin_amdgcn_mfma_f32_16x16x32_bf16(af, bf, acc[f], 0, 0, 0);
    }
  }

  int orow = rbase + ((lane >> 4) << 2);
  float msk[4][3];
#pragma unroll
  for (int reg = 0; reg < 4; ++reg) {
    int nd = orow + reg; if (nd > 49999) nd = 49999;
#pragma unroll
    for (int r = 0; r < 3; ++r)
      msk[reg][r] = (deg1[r * 50000 + nd] > 0.0f) ? 1.0f : 0.0f;
  }
#pragma unroll
  for (int f = 0; f < 8; ++f) {
    int col = (f << 4) + (lane & 15);
    float bb0 = b1[col], bb1 = b1[128 + col], bb2 = b1[256 + col];
#pragma unroll
    for (int reg = 0; reg < 4; ++reg) {
      int nd = orow + reg;
      if (nd < 50000) {
        float v = acc[f][reg] + msk[reg][0] * bb0 + msk[reg][1] * bb1 + msk[reg][2] * bb2;
        v = (v >= 0.f) ? v : 0.01f * v;
        hb[(nd << 7) + col] = f2bf(v);
      }
    }
  }
}

// ---- GEMM2: Wh2[r] = h @ W2_r + b2_r, bf16 out. M=50000, N=192 (12 frags), K=128 ----
__global__ __launch_bounds__(256) void gemm2_k(
    const unsigned short* __restrict__ hb, const unsigned short* __restrict__ w2t,
    const float* __restrict__ b2, unsigned short* __restrict__ wh2) {
  int lane = threadIdx.x & 63;
  int wave = threadIdx.x >> 6;
  int rbase = blockIdx.x * 64 + wave * 16;
  int arow = rbase + (lane & 15);
  int anode = arow < 50000 ? arow : 49999;
  int kg = lane >> 4;

  const floatx4 fzero = {0.f, 0.f, 0.f, 0.f};
  floatx4 acc[12];
#pragma unroll
  for (int f = 0; f < 12; ++f) acc[f] = fzero;

#pragma unroll
  for (int ks = 0; ks < 4; ++ks) {
    int k0 = (ks << 5) + (kg << 3);
    short8 af = *(const short8*)(hb + (anode << 7) + k0);
#pragma unroll
    for (int f = 0; f < 12; ++f) {
      int col = (f << 4) + (lane & 15);
      int r = col >> 6, c0 = col & 63;
      short8 bf = *(const short8*)(w2t + (r << 13) + (c0 << 7) + k0);
      acc[f] = __builtin_amdgcn_mfma_f32_16x16x32_bf16(af, bf, acc[f], 0, 0, 0);
    }
  }
  int orow = rbase + ((lane >> 4) << 2);
#pragma unroll
  for (int f = 0; f < 12; ++f) {
    int col = (f << 4) + (lane & 15);
    int r = col >> 6, c0 = col & 63;
    float bv = b2[(r << 6) + c0];
#pragma unroll
    for (int reg = 0; reg < 4; ++reg) {
      int nd = orow + reg;
      if (nd < 50000) {
        float v = acc[f][reg] + bv;
        wh2[((r * 50000 + nd) << 6) + c0] = f2bf(v);
      }
    }
  }
}

// ---- final: out[v][c] = sum_r s2[r][v][c] / max(deg2[r][v],1) ----
__global__ __launch_bounds__(256) void final_k(
    const float* __restrict__ s2, const float* __restrict__ deg2,
    float* __restrict__ out) {
  int tid = blockIdx.x * 256 + threadIdx.x;
  if (tid >= 800000) return;            // 50000 * 16 float4s
  int v = tid >> 4, c4 = (tid & 15) << 2;
  float ox = 0.f, oy = 0.f, oz = 0.f, ow = 0.f;
#pragma unroll
  for (int r = 0; r < 3; ++r) {
    float dg = deg2[r * 50000 + v];
    float inv = 1.0f / fmaxf(dg, 1.0f);
    const float4 s = *(const float4*)(s2 + ((r * 50000 + v) << 6) + c4);
    ox += s.x * inv; oy += s.y * inv; oz += s.z * inv; ow += s.w * inv;
  }
  float4 o; o.x = ox; o.y = oy; o.z = oz; o.w = ow;
  ((float4*)out)[tid] = o;
}

extern "C" void kernel_launch(void* const* d_in, const int* in_sizes, int n_in,
                              void* d_out, int out_size, void* d_ws, size_t ws_size,
                              hipStream_t stream) {
  const float* feat = (const float*)d_in[0];
  const float* W1   = (const float*)d_in[1];
  const float* b1   = (const float*)d_in[2];
  const float* W2   = (const float*)d_in[3];
  const float* b2   = (const float*)d_in[4];
  const int* es1 = (const int*)d_in[5];
  const int* ed1 = (const int*)d_in[6];
  const int* es2 = (const int*)d_in[7];
  const int* ed2 = (const int*)d_in[8];

  char* ws = (char*)d_ws;
  float* s1   = (float*)(ws + 0);          // 3*50000*128*4 = 76,800,000
  float* s2   = (float*)(ws + 76800000);   // 3*50000*64*4  = 38,400,000
  float* deg1 = (float*)(ws + 115200000);  // 600,000
  float* deg2 = (float*)(ws + 115800000);  // 600,000
  unsigned short* featb = (unsigned short*)(ws + 116400000);  // 12,800,000
  unsigned short* hb    = (unsigned short*)(ws + 129200000);  // 12,800,000
  unsigned short* wh2   = (unsigned short*)(ws + 142000000);  // 19,200,000
  unsigned short* w1t   = (unsigned short*)(ws + 161200000);  // 98,304
  unsigned short* w2t   = (unsigned short*)(ws + 161298304);  // 49,152

  hipMemsetAsync(ws, 0, 116400000, stream);  // zero s1, s2, deg1, deg2
  prep_k<<<6538, 256, 0, stream>>>(feat, W1, W2, featb, w1t, w2t);
  agg1_k<<<8192, 256, 0, stream>>>(es1, ed1, featb, s1, deg1);
  gemm1_k<<<782, 256, 0, stream>>>(s1, deg1, w1t, b1, hb);
  gemm2_k<<<782, 256, 0, stream>>>(hb, w2t, b2, wh2);
  agg2_k<<<8192, 256, 0, stream>>>(es2, ed2, wh2, s2, deg2);
  final_k<<<3125, 256, 0, stream>>>(s2, deg2, (float*)d_out);
}

// Round 2
// 966.244 us; speedup vs baseline: 2.9858x; 2.9858x over previous
//
#include <hip/hip_runtime.h>

typedef __attribute__((ext_vector_type(8))) short short8;
typedef __attribute__((ext_vector_type(4))) float floatx4;

__device__ __forceinline__ unsigned short f2bf(float f) {
  unsigned u = __float_as_uint(f);
  u += 0x7FFFu + ((u >> 16) & 1u);
  return (unsigned short)(u >> 16);
}
__device__ __forceinline__ float bf2f(unsigned short b) {
  return __uint_as_float(((unsigned)b) << 16);
}

// ---- prep: feat->bf16; W1 [3,128,128] -> W1T [3][n=128][k=128] bf16;
//            W2 [3,128,64] -> W2T [3][n=64][k=128] bf16 ----
__global__ __launch_bounds__(256) void prep_k(
    const float* __restrict__ feat, const float* __restrict__ W1,
    const float* __restrict__ W2, unsigned short* __restrict__ featb,
    unsigned short* __restrict__ w1t, unsigned short* __restrict__ w2t) {
  int tid = blockIdx.x * 256 + threadIdx.x;
  if (tid < 1600000) {                    // 50000*128/4 float4s
    float4 v = ((const float4*)feat)[tid];
    ushort4 o;
    o.x = f2bf(v.x); o.y = f2bf(v.y); o.z = f2bf(v.z); o.w = f2bf(v.w);
    ((ushort4*)featb)[tid] = o;
  } else if (tid < 1600000 + 49152) {     // W1T
    int t = tid - 1600000;
    int r = t >> 14, rem = t & 16383, n = rem >> 7, k = rem & 127;
    w1t[t] = f2bf(W1[(r << 14) + (k << 7) + n]);
  } else if (tid < 1600000 + 49152 + 24576) {  // W2T
    int t = tid - 1649152;
    int r = t >> 13, rem = t & 8191, n = rem >> 7, k = rem & 127;
    w2t[t] = f2bf(W2[(r << 13) + (k << 6) + n]);
  }
}

// ---- CSR build: histogram of (layer, r, dst) ----
__global__ __launch_bounds__(256) void hist_k(
    const int* __restrict__ ed1, const int* __restrict__ ed2,
    int* __restrict__ cntall) {
  int i = blockIdx.x * 256 + threadIdx.x;  // 4.8M
  const int* ed; int ofs, j;
  if (i < 2400000) { ed = ed1; ofs = 0; j = i; }
  else             { ed = ed2; ofs = 150000; j = i - 2400000; }
  int r = j / 800000;
  atomicAdd(cntall + ofs + r * 50000 + ed[j], 1);
}

// ---- CSR build: allocate bucket bases via wave-aggregated cursor atomics ----
__global__ __launch_bounds__(256) void alloc_k(
    const int* __restrict__ cntall, int* __restrict__ offall,
    int* __restrict__ posall, int* __restrict__ cur) {
  int t = blockIdx.x * 256 + threadIdx.x;
  if (t >= 300032) return;                 // 2 layers x 150016 (wave-padded)
  int lane = threadIdx.x & 63;
  int layer = t / 150016;
  int i = t - layer * 150016;
  int c = (i < 150000) ? cntall[layer * 150000 + i] : 0;
  // wave inclusive scan
  int sum = c;
#pragma unroll
  for (int o = 1; o < 64; o <<= 1) {
    int u = __shfl_up(sum, o);
    if (lane >= o) sum += u;
  }
  int total = __shfl(sum, 63);
  int base = 0;
  if (lane == 63) base = atomicAdd(cur + layer, total);
  base = __shfl(base, 63);
  if (i < 150000) {
    int v = base + sum - c;                // exclusive
    offall[layer * 150000 + i] = v;
    posall[layer * 150000 + i] = v;
  }
}

// ---- CSR build: scatter src ids into buckets ----
__global__ __launch_bounds__(256) void scatter_k(
    const int* __restrict__ es1, const int* __restrict__ ed1,
    const int* __restrict__ es2, const int* __restrict__ ed2,
    int* __restrict__ posall, int* __restrict__ eidx1,
    int* __restrict__ eidx2) {
  int i = blockIdx.x * 256 + threadIdx.x;  // 4.8M
  const int *es, *ed; int* eidx; int ofs, j;
  if (i < 2400000) { es = es1; ed = ed1; eidx = eidx1; ofs = 0; j = i; }
  else { es = es2; ed = ed2; eidx = eidx2; ofs = 150000; j = i - 2400000; }
  int r = j / 800000;
  int p = atomicAdd(posall + ofs + r * 50000 + ed[j], 1);
  eidx[p] = es[j];
}

// ---- layer-1 aggregation, CSR: one wave per node, write mean as bf16 ----
__global__ __launch_bounds__(256) void agg1_k(
    const int* __restrict__ offall, const int* __restrict__ cntall,
    const int* __restrict__ eidx1, const unsigned short* __restrict__ featb,
    unsigned short* __restrict__ s1m) {
  int lane = threadIdx.x & 63;
  int v = blockIdx.x * 4 + (threadIdx.x >> 6);
  if (v >= 50000) return;
  const unsigned* fb = (const unsigned*)featb + lane;  // featb row + lane*2 shorts
#pragma unroll
  for (int r = 0; r < 3; ++r) {
    int rd = r * 50000 + v;
    int base = offall[rd], n = cntall[rd];
    float a0 = 0.f, a1 = 0.f;
    for (int jb = 0; jb < n; jb += 64) {
      int m = n - jb; if (m > 64) m = 64;
      int my = (lane < m) ? eidx1[base + jb + lane] : 0;
      int k = 0;
      for (; k + 4 <= m; k += 4) {
        int s0 = __shfl(my, k), s1 = __shfl(my, k + 1);
        int s2 = __shfl(my, k + 2), s3 = __shfl(my, k + 3);
        unsigned p0 = fb[s0 << 6], p1 = fb[s1 << 6];
        unsigned p2 = fb[s2 << 6], p3 = fb[s3 << 6];
        a0 += __uint_as_float(p0 << 16) + __uint_as_float(p1 << 16) +
              __uint_as_float(p2 << 16) + __uint_as_float(p3 << 16);
        a1 += __uint_as_float(p0 & 0xFFFF0000u) + __uint_as_float(p1 & 0xFFFF0000u) +
              __uint_as_float(p2 & 0xFFFF0000u) + __uint_as_float(p3 & 0xFFFF0000u);
      }
      for (; k < m; ++k) {
        int s = __shfl(my, k);
        unsigned p = fb[s << 6];
        a0 += __uint_as_float(p << 16);
        a1 += __uint_as_float(p & 0xFFFF0000u);
      }
    }
    float inv = 1.0f / fmaxf((float)n, 1.0f);
    unsigned short b0 = f2bf(a0 * inv), b1 = f2bf(a1 * inv);
    *((unsigned*)(s1m + (rd << 7)) + lane) = ((unsigned)b1 << 16) | (unsigned)b0;
  }
}

// ---- layer-2 aggregation + final, CSR: one wave per node, writes out f32 ----
__global__ __launch_bounds__(256) void agg2f_k(
    const int* __restrict__ offall, const int* __restrict__ cntall,
    const int* __restrict__ eidx2, const unsigned short* __restrict__ wh2,
    float* __restrict__ out) {
  int lane = threadIdx.x & 63;
  int v = blockIdx.x * 4 + (threadIdx.x >> 6);
  if (v >= 50000) return;
  float o = 0.f;
#pragma unroll
  for (int r = 0; r < 3; ++r) {
    int rd = r * 50000 + v;
    int base = offall[150000 + rd], n = cntall[150000 + rd];
    const unsigned short* wb = wh2 + ((long)r * 50000 << 6) + lane;
    float a = 0.f;
    for (int jb = 0; jb < n; jb += 64) {
      int m = n - jb; if (m > 64) m = 64;
      int my = (lane < m) ? eidx2[base + jb + lane] : 0;
      int k = 0;
      for (; k + 4 <= m; k += 4) {
        int s0 = __shfl(my, k), s1 = __shfl(my, k + 1);
        int s2 = __shfl(my, k + 2), s3 = __shfl(my, k + 3);
        a += bf2f(wb[s0 << 6]) + bf2f(wb[s1 << 6]) +
             bf2f(wb[s2 << 6]) + bf2f(wb[s3 << 6]);
      }
      for (; k < m; ++k) a += bf2f(wb[__shfl(my, k) << 6]);
    }
    o += a / fmaxf((float)n, 1.0f);
  }
  out[(v << 6) + lane] = o;
}

// ---- GEMM1: h = leaky( sum_r s1m_r @ W1_r + b1_r*[cnt>0] ), bf16 out ----
__global__ __launch_bounds__(256) void gemm1_k(
    const unsigned short* __restrict__ s1m, const int* __restrict__ cnt1,
    const unsigned short* __restrict__ w1t, const float* __restrict__ b1,
    unsigned short* __restrict__ hb) {
  int lane = threadIdx.x & 63;
  int wave = threadIdx.x >> 6;
  int rbase = blockIdx.x * 64 + wave * 16;
  int arow = rbase + (lane & 15);
  int anode = arow < 50000 ? arow : 49999;
  int kg = lane >> 4;

  const floatx4 fzero = {0.f, 0.f, 0.f, 0.f};
  floatx4 acc[8];
#pragma unroll
  for (int f = 0; f < 8; ++f) acc[f] = fzero;

#pragma unroll
  for (int ks = 0; ks < 12; ++ks) {
    int r = ks >> 2;
    int k0 = ((ks & 3) << 5) + (kg << 3);
    short8 af = *(const short8*)(s1m + ((r * 50000 + anode) << 7) + k0);
#pragma unroll
    for (int f = 0; f < 8; ++f) {
      int n = (f << 4) + (lane & 15);
      short8 bf = *(const short8*)(w1t + (r << 14) + (n << 7) + k0);
      acc[f] = __builtin_amdgcn_mfma_f32_16x16x32_bf16(af, bf, acc[f], 0, 0, 0);
    }
  }

  int orow = rbase + ((lane >> 4) << 2);
  float msk[4][3];
#pragma unroll
  for (int reg = 0; reg < 4; ++reg) {
    int nd = orow + reg; if (nd > 49999) nd = 49999;
#pragma unroll
    for (int r = 0; r < 3; ++r)
      msk[reg][r] = cnt1[r * 50000 + nd] ? 1.0f : 0.0f;
  }
#pragma unroll
  for (int f = 0; f < 8; ++f) {
    int col = (f << 4) + (lane & 15);
    float bb0 = b1[col], bb1 = b1[128 + col], bb2 = b1[256 + col];
#pragma unroll
    for (int reg = 0; reg < 4; ++reg) {
      int nd = orow + reg;
      if (nd < 50000) {
        float v = acc[f][reg] + msk[reg][0] * bb0 + msk[reg][1] * bb1 + msk[reg][2] * bb2;
        v = (v >= 0.f) ? v : 0.01f * v;
        hb[(nd << 7) + col] = f2bf(v);
      }
    }
  }
}

// ---- GEMM2: Wh2[r] = h @ W2_r + b2_r, bf16 out. M=50000, N=192, K=128 ----
__global__ __launch_bounds__(256) void gemm2_k(
    const unsigned short* __restrict__ hb, const unsigned short* __restrict__ w2t,
    const float* __restrict__ b2, unsigned short* __restrict__ wh2) {
  int lane = threadIdx.x & 63;
  int wave = threadIdx.x >> 6;
  int rbase = blockIdx.x * 64 + wave * 16;
  int arow = rbase + (lane & 15);
  int anode = arow < 50000 ? arow : 49999;
  int kg = lane >> 4;

  const floatx4 fzero = {0.f, 0.f, 0.f, 0.f};
  floatx4 acc[12];
#pragma unroll
  for (int f = 0; f < 12; ++f) acc[f] = fzero;

#pragma unroll
  for (int ks = 0; ks < 4; ++ks) {
    int k0 = (ks << 5) + (kg << 3);
    short8 af = *(const short8*)(hb + (anode << 7) + k0);
#pragma unroll
    for (int f = 0; f < 12; ++f) {
      int col = (f << 4) + (lane & 15);
      int r = col >> 6, c0 = col & 63;
      short8 bf = *(const short8*)(w2t + (r << 13) + (c0 << 7) + k0);
      acc[f] = __builtin_amdgcn_mfma_f32_16x16x32_bf16(af, bf, acc[f], 0, 0, 0);
    }
  }
  int orow = rbase + ((lane >> 4) << 2);
#pragma unroll
  for (int f = 0; f < 12; ++f) {
    int col = (f << 4) + (lane & 15);
    int r = col >> 6, c0 = col & 63;
    float bv = b2[(r << 6) + c0];
#pragma unroll
    for (int reg = 0; reg < 4; ++reg) {
      int nd = orow + reg;
      if (nd < 50000) {
        float v = acc[f][reg] + bv;
        wh2[((r * 50000 + nd) << 6) + c0] = f2bf(v);
      }
    }
  }
}

extern "C" void kernel_launch(void* const* d_in, const int* in_sizes, int n_in,
                              void* d_out, int out_size, void* d_ws, size_t ws_size,
                              hipStream_t stream) {
  const float* feat = (const float*)d_in[0];
  const float* W1   = (const float*)d_in[1];
  const float* b1   = (const float*)d_in[2];
  const float* W2   = (const float*)d_in[3];
  const float* b2   = (const float*)d_in[4];
  const int* es1 = (const int*)d_in[5];
  const int* ed1 = (const int*)d_in[6];
  const int* es2 = (const int*)d_in[7];
  const int* ed2 = (const int*)d_in[8];

  char* ws = (char*)d_ws;
  int* cntall = (int*)(ws + 0);            // [2][150000] ints = 1,200,000 B
  int* cur    = (int*)(ws + 1200000);      // 2 ints (memset with cnt)
  int* offall = (int*)(ws + 1200128);      // [2][150000]
  int* posall = (int*)(ws + 2400128);      // [2][150000]
  int* eidx1  = (int*)(ws + 3600128);      // 2.4M ints = 9.6 MB
  int* eidx2  = (int*)(ws + 13200128);     // 9.6 MB
  unsigned short* featb = (unsigned short*)(ws + 22800128);  // 12.8 MB
  unsigned short* s1m   = (unsigned short*)(ws + 35600128);  // 38.4 MB
  unsigned short* hb    = (unsigned short*)(ws + 74000128);  // 12.8 MB
  unsigned short* wh2   = (unsigned short*)(ws + 86800128);  // 19.2 MB
  unsigned short* w1t   = (unsigned short*)(ws + 106000128); // 98,304
  unsigned short* w2t   = (unsigned short*)(ws + 106098432); // 49,152

  hipMemsetAsync(ws, 0, 1200128, stream);  // cnt1, cnt2, cursors
  prep_k<<<6538, 256, 0, stream>>>(feat, W1, W2, featb, w1t, w2t);
  hist_k<<<18750, 256, 0, stream>>>(ed1, ed2, cntall);
  alloc_k<<<1173, 256, 0, stream>>>(cntall, offall, posall, cur);
  scatter_k<<<18750, 256, 0, stream>>>(es1, ed1, es2, ed2, posall, eidx1, eidx2);
  agg1_k<<<12500, 256, 0, stream>>>(offall, cntall, eidx1, featb, s1m);
  gemm1_k<<<782, 256, 0, stream>>>(s1m, cntall, w1t, b1, hb);
  gemm2_k<<<782, 256, 0, stream>>>(hb, w2t, b2, wh2);
  agg2f_k<<<12500, 256, 0, stream>>>(offall, cntall, eidx2, wh2, (float*)d_out);
}